// Round 4
// baseline (489.716 us; speedup 1.0000x reference)
//
#include <hip/hip_runtime.h>
#include <hip/hip_bf16.h>
#include <cstdint>

#define TK 2048      // tokens (2*1024)
#define HD 2048      // hidden
#define ID 1024      // intermediate
#define NE 16        // routed experts
#define NG 17        // groups incl shared expert (g==16)
#define TOPK 4
#define SLOTS (TK*TOPK)       // 8192 routed rows
#define ROWS_ALL (SLOTS+TK)   // 10240 incl shared
#define IH (ID*HD)            // 2,097,152 elems per expert matrix
#define MAXT 96               // max M-tiles across all groups

typedef __attribute__((ext_vector_type(4))) float f32x4;
typedef __attribute__((ext_vector_type(8))) short s16x8;
typedef unsigned short u16;
typedef unsigned long long u64;

__device__ __forceinline__ u16 f2bf(float f){
  union { float f; uint32_t u; } v; v.f = f;
  uint32_t r = v.u + 0x7fffu + ((v.u >> 16) & 1u);  // RNE
  return (u16)(r >> 16);
}

// pack 8 fp32 -> 8 bf16 (RNE) as one uint4
__device__ __forceinline__ uint4 pack8(float4 a, float4 b){
  u16 h[8];
  h[0]=f2bf(a.x); h[1]=f2bf(a.y); h[2]=f2bf(a.z); h[3]=f2bf(a.w);
  h[4]=f2bf(b.x); h[5]=f2bf(b.y); h[6]=f2bf(b.z); h[7]=f2bf(b.w);
  return *(uint4*)h;
}

// async global->LDS, 16B per lane; LDS dest is wave-uniform base + lane*16
#define GLD16(g, l) __builtin_amdgcn_global_load_lds( \
    (const __attribute__((address_space(1))) void*)(g), \
    (__attribute__((address_space(3))) void*)(l), 16, 0, 0)

// swizzled fragment pointer: 128B rows, byte ^= ((row&7)<<4)
__device__ __forceinline__ const s16x8* fragp(const u16* b, int row, int off){
  return (const s16x8*)((const char*)b + row*128 + (off ^ ((row&7)<<4)));
}

// ---------------- prep: zero out, init maskbits, convert x ----------------
__global__ void k_prep(const float* __restrict__ x, u16* __restrict__ xb,
                       float* __restrict__ out, int out_n, u64* __restrict__ maskbits){
  int gi = blockIdx.x*blockDim.x + threadIdx.x;
  int st = gridDim.x*blockDim.x;
  if (gi < NE*32) maskbits[gi] = 0ull;
  for (int i=gi; i<out_n; i+=st) out[i] = 0.f;
  for (int i=gi; i<TK*HD/4; i+=st){
    float4 f = ((const float4*)x)[i];
    ushort4 o; o.x=f2bf(f.x); o.y=f2bf(f.y); o.z=f2bf(f.z); o.w=f2bf(f.w);
    ((ushort4*)xb)[i] = o;
  }
}

// ---------------- router: logits + sigmoid + top-4 select (fused) ----------------
__global__ __launch_bounds__(256) void k_logits(const float* __restrict__ x,
                                                const float* __restrict__ gw,
                                                const float* __restrict__ bias,
                                                float* __restrict__ wdense,
                                                u64* __restrict__ maskbits){
  int t = blockIdx.x, tid = threadIdx.x;
  int lane = tid & 63, wv = tid >> 6;
  const float* xr = x + (size_t)t*HD;
  float acc[NE];
  #pragma unroll
  for (int e=0;e<NE;e++) acc[e]=0.f;
  for (int k=tid;k<HD;k+=256){
    float xv = xr[k];
    #pragma unroll
    for (int e=0;e<NE;e++) acc[e] += xv * gw[e*HD + k];
  }
  __shared__ float red[NE][4];
  #pragma unroll
  for (int e=0;e<NE;e++){
    float v = acc[e];
    #pragma unroll
    for (int off=32;off>0;off>>=1) v += __shfl_down(v, off, 64);
    if (lane==0) red[e][wv] = v;
  }
  __syncthreads();
  if (tid == 0){
    float sc[NE], bs[NE];
    #pragma unroll
    for (int e=0;e<NE;e++){
      float l = red[e][0]+red[e][1]+red[e][2]+red[e][3];
      float s = 1.f/(1.f+expf(-l));
      sc[e]=s; bs[e]=s+bias[e];
    }
    int idx[TOPK]; float wsum=0.f; unsigned used=0;
    for (int k=0;k<TOPK;k++){
      int best=0; float bv=-1e30f;
      for (int e=0;e<NE;e++) if (!((used>>e)&1u) && bs[e] > bv){ bv=bs[e]; best=e; }
      used |= 1u<<best; idx[k]=best; wsum += sc[best];
    }
    float inv = 1.f/wsum;
    for (int k=0;k<TOPK;k++){
      int e = idx[k];
      wdense[t*NE + e] = sc[e]*inv;
      atomicOr(&maskbits[e*32 + (t>>6)], 1ull << (t&63));
    }
  }
}

// prefix sums + dense tile table (tiny, 1 thread — deterministic)
__global__ void k_scan(const u64* __restrict__ maskbits, int* __restrict__ counts,
                       int* __restrict__ offsets, int* __restrict__ wordpfx,
                       int* __restrict__ tiles){
  int acc = 0;
  for (int e=0;e<NE;e++){
    int c = 0;
    for (int w=0;w<32;w++){ wordpfx[e*32+w] = c; c += __popcll(maskbits[e*32+w]); }
    counts[e] = c;
  }
  for (int e=0;e<NE;e++){ offsets[e] = acc; acc += counts[e]; }
  offsets[NE] = acc;   // == SLOTS
  counts[NE] = TK;     // shared expert
  int nt = 0;
  for (int g=0; g<NG; g++){
    int c = counts[g];
    for (int mt=0; mt*128 < c && nt < MAXT; mt++) tiles[nt++] = (g<<8) | mt;
  }
  for (; nt<MAXT; nt++) tiles[nt] = -1;
}

// deterministic compaction via popcount rank
__global__ void k_scatter(const u64* __restrict__ maskbits, const int* __restrict__ offsets,
                          const int* __restrict__ wordpfx, const float* __restrict__ wdense,
                          int* __restrict__ rowtok, float* __restrict__ roww){
  int t = blockIdx.x*blockDim.x + threadIdx.x;
  int e = blockIdx.y;
  if (t >= TK) return;
  if (e == NE){ rowtok[offsets[NE]+t] = t; roww[offsets[NE]+t] = 1.f; return; }
  u64 w = maskbits[e*32 + (t>>6)];
  if ((w >> (t&63)) & 1ull){
    int pos = offsets[e] + wordpfx[e*32 + (t>>6)] + __popcll(w & ((1ull << (t&63)) - 1ull));
    rowtok[pos] = t; roww[pos] = wdense[t*NE + e];
  }
}

// ============ GEMM1: P = silu(X Wg^T)*(X Wu^T)*roww ============
// BM=128, BN=64 (gate+up), BK=64; fp32 weights reg-staged->bf16->LDS;
// A (bf16) via global_load_lds; double-buffered stage-early pipeline.
__global__ __launch_bounds__(256) void k_gemm1(
    const u16* __restrict__ xb,
    const float* __restrict__ w_gate, const float* __restrict__ w_up,
    const float* __restrict__ sw_gate, const float* __restrict__ sw_up,
    const int* __restrict__ counts, const int* __restrict__ offsets,
    const int* __restrict__ rowtok, const float* __restrict__ roww,
    const int* __restrict__ tiles, u16* __restrict__ P)
{
  int te = tiles[blockIdx.y];
  if (te < 0) return;
  int g = te >> 8, mt = te & 255;
  int cnt = counts[g];
  int n0 = blockIdx.x*64;
  int base = offsets[g];
  const float* wg32 = (g<NE) ? w_gate + (size_t)g*IH : sw_gate;
  const float* wu32 = (g<NE) ? w_up   + (size_t)g*IH : sw_up;

  __shared__ u16 lsA[2][128*64];   // 2 x 16 KB
  __shared__ u16 lsG[2][64*64];    // 2 x 8 KB
  __shared__ u16 lsU[2][64*64];    // 2 x 8 KB

  int tid = threadIdx.x, lane = tid & 63, wv = tid >> 6;
  int wm = (wv>>1)*64, wn = (wv&1)*32;
  int rl = lane & 15, hi = lane >> 4;

  f32x4 accg[4][2] = {}; f32x4 accu[4][2] = {};

  // A staging sources (pre-swizzled cols so linear LDS dest + swizzled read work)
  const u16* aSrc[4];
  #pragma unroll
  for (int i=0;i<4;i++){
    int b = i*256 + tid, r = b>>3, cb = b&7;
    int m = mt*128 + r; if (m >= cnt) m = cnt-1;
    int tok = rowtok[base + m];
    aSrc[i] = xb + (size_t)tok*HD + ((cb ^ (r&7))<<3);
  }
  // W staging: thread -> (row, 16-col quad); 16 fp32 per thread per matrix
  int wrow = tid>>2, wq = tid&3;
  const float* gW = wg32 + (size_t)(n0+wrow)*HD + wq*16;
  const float* uW = wu32 + (size_t)(n0+wrow)*HD + wq*16;
  int wb0 = (wrow*128 + wq*32) ^ ((wrow&7)<<4);   // swizzled byte offset (first 16B)
  char* gBase = (char*)&lsG[0][0];
  char* uBase = (char*)&lsU[0][0];

  float4 gr[4], ur[4];
  // ---- prologue: tile 0 ----
  #pragma unroll
  for (int j=0;j<4;j++){ gr[j] = ((const float4*)gW)[j]; ur[j] = ((const float4*)uW)[j]; }
  #pragma unroll
  for (int i=0;i<4;i++) GLD16(aSrc[i], &lsA[0][(i*256 + wv*64)*8]);
  {
    uint4 g0 = pack8(gr[0],gr[1]), g1 = pack8(gr[2],gr[3]);
    uint4 u0 = pack8(ur[0],ur[1]), u1 = pack8(ur[2],ur[3]);
    *(uint4*)(gBase + wb0)      = g0;
    *(uint4*)(gBase + (wb0^16)) = g1;
    *(uint4*)(uBase + wb0)      = u0;
    *(uint4*)(uBase + (wb0^16)) = u1;
  }
  __syncthreads();

  const int ntile = HD/64;
  for (int t=0; t<ntile; ++t){
    int cur = t & 1, nxt = cur ^ 1;
    bool more = (t+1 < ntile);
    int k1 = (t+1)*64;
    if (more){
      #pragma unroll
      for (int j=0;j<4;j++){ gr[j] = ((const float4*)(gW+k1))[j]; ur[j] = ((const float4*)(uW+k1))[j]; }
      #pragma unroll
      for (int i=0;i<4;i++) GLD16(aSrc[i]+k1, &lsA[nxt][(i*256 + wv*64)*8]);
    }
    // compute on cur
    const u16* A = lsA[cur]; const u16* G = lsG[cur]; const u16* U = lsU[cur];
    #pragma unroll
    for (int ks=0; ks<2; ++ks){
      int off = ks*64 + hi*16;
      s16x8 af[4];
      #pragma unroll
      for (int mi=0;mi<4;mi++) af[mi] = *fragp(A, wm+16*mi+rl, off);
      #pragma unroll
      for (int ni=0;ni<2;ni++){
        s16x8 bg = *fragp(G, wn+16*ni+rl, off);
        s16x8 bu = *fragp(U, wn+16*ni+rl, off);
        #pragma unroll
        for (int mi=0;mi<4;mi++){
          accg[mi][ni] = __builtin_amdgcn_mfma_f32_16x16x32_bf16(af[mi], bg, accg[mi][ni], 0,0,0);
          accu[mi][ni] = __builtin_amdgcn_mfma_f32_16x16x32_bf16(af[mi], bu, accu[mi][ni], 0,0,0);
        }
      }
    }
    if (more){
      uint4 g0 = pack8(gr[0],gr[1]), g1 = pack8(gr[2],gr[3]);
      uint4 u0 = pack8(ur[0],ur[1]), u1 = pack8(ur[2],ur[3]);
      char* gd = gBase + nxt*8192; char* ud = uBase + nxt*8192;
      *(uint4*)(gd + wb0)      = g0;
      *(uint4*)(gd + (wb0^16)) = g1;
      *(uint4*)(ud + wb0)      = u0;
      *(uint4*)(ud + (wb0^16)) = u1;
    }
    __syncthreads();
  }
  // epilogue: SwiGLU * token weight -> bf16 P
  int rl4 = hi*4, cl = rl;
  #pragma unroll
  for (int mi=0;mi<4;mi++){
    #pragma unroll
    for (int j=0;j<4;j++){
      int m = mt*128 + wm + mi*16 + rl4 + j;
      if (m < cnt){
        int slot = base + m;
        float wgt = roww[slot];
        #pragma unroll
        for (int ni=0;ni<2;ni++){
          float gv = accg[mi][ni][j], uv = accu[mi][ni][j];
          float pv = gv/(1.f+expf(-gv))*uv*wgt;
          P[(size_t)slot*ID + n0 + wn + ni*16 + cl] = f2bf(pv);
        }
      }
    }
  }
}

// ============ GEMM2: out[tok] += P @ Wd^T ============
// BM=128, BN=128, BK=64; fp32 w_down reg-staged; P via global_load_lds; dbuf pipeline
__global__ __launch_bounds__(256) void k_gemm2(
    const u16* __restrict__ P,
    const float* __restrict__ w_down, const float* __restrict__ sw_down,
    const int* __restrict__ counts, const int* __restrict__ offsets,
    const int* __restrict__ rowtok, const int* __restrict__ tiles,
    float* __restrict__ out)
{
  int te = tiles[blockIdx.y];
  if (te < 0) return;
  int g = te >> 8, mt = te & 255;
  int cnt = counts[g];
  int n0 = blockIdx.x*128;
  int base = offsets[g];
  const float* wd32 = (g<NE) ? w_down + (size_t)g*IH : sw_down;

  __shared__ u16 lsA[2][128*64];   // 2 x 16 KB
  __shared__ u16 lsB[2][128*64];   // 2 x 16 KB

  int tid = threadIdx.x, lane = tid & 63, wv = tid >> 6;
  int wm = (wv>>1)*64, wn = (wv&1)*64;
  int rl = lane & 15, hi = lane >> 4;
  f32x4 acc[4][4] = {};

  const u16* aSrc[4];
  #pragma unroll
  for (int i=0;i<4;i++){
    int b = i*256 + tid, r = b>>3, cb = b&7;
    int m = mt*128 + r; if (m >= cnt) m = cnt-1;
    aSrc[i] = P + (size_t)(base + m)*ID + ((cb ^ (r&7))<<3);
  }
  // B staging: thread -> (row, half); 32 fp32 per thread
  int brow = tid>>1, bh = tid&1;
  const float* bW = wd32 + (size_t)(n0+brow)*ID + bh*32;
  int bb = (brow*128 + bh*64) ^ ((brow&7)<<4);   // swizzled base byte
  char* bBase = (char*)&lsB[0][0];

  float4 br[8];
  // ---- prologue ----
  #pragma unroll
  for (int j=0;j<8;j++) br[j] = ((const float4*)bW)[j];
  #pragma unroll
  for (int i=0;i<4;i++) GLD16(aSrc[i], &lsA[0][(i*256 + wv*64)*8]);
  {
    #pragma unroll
    for (int c=0;c<4;c++){
      uint4 w = pack8(br[2*c], br[2*c+1]);
      *(uint4*)(bBase + (bb ^ (c*16))) = w;
    }
  }
  __syncthreads();

  const int ntile = ID/64;
  for (int t=0; t<ntile; ++t){
    int cur = t & 1, nxt = cur ^ 1;
    bool more = (t+1 < ntile);
    int k1 = (t+1)*64;
    if (more){
      #pragma unroll
      for (int j=0;j<8;j++) br[j] = ((const float4*)(bW+k1))[j];
      #pragma unroll
      for (int i=0;i<4;i++) GLD16(aSrc[i]+k1, &lsA[nxt][(i*256 + wv*64)*8]);
    }
    const u16* A = lsA[cur]; const u16* B = lsB[cur];
    #pragma unroll
    for (int ks=0; ks<2; ++ks){
      int off = ks*64 + hi*16;
      s16x8 af[4], bf[4];
      #pragma unroll
      for (int mi=0;mi<4;mi++) af[mi] = *fragp(A, wm+16*mi+rl, off);
      #pragma unroll
      for (int ni=0;ni<4;ni++) bf[ni] = *fragp(B, wn+16*ni+rl, off);
      #pragma unroll
      for (int mi=0;mi<4;mi++)
        #pragma unroll
        for (int ni=0;ni<4;ni++)
          acc[mi][ni] = __builtin_amdgcn_mfma_f32_16x16x32_bf16(af[mi], bf[ni], acc[mi][ni], 0,0,0);
    }
    if (more){
      char* bd = bBase + nxt*16384;
      #pragma unroll
      for (int c=0;c<4;c++){
        uint4 w = pack8(br[2*c], br[2*c+1]);
        *(uint4*)(bd + (bb ^ (c*16))) = w;
      }
    }
    __syncthreads();
  }
  int rl4 = hi*4, cl = rl;
  #pragma unroll
  for (int mi=0;mi<4;mi++){
    #pragma unroll
    for (int j=0;j<4;j++){
      int m = mt*128 + wm + mi*16 + rl4 + j;
      if (m < cnt){
        int tok = rowtok[base + m];
        #pragma unroll
        for (int ni=0;ni<4;ni++)
          atomicAdd(&out[(size_t)tok*HD + n0 + wn + ni*16 + cl], acc[mi][ni][j]);
      }
    }
  }
}

// ---------------- host ----------------

extern "C" void kernel_launch(void* const* d_in, const int* in_sizes, int n_in,
                              void* d_out, int out_size, void* d_ws, size_t ws_size,
                              hipStream_t stream){
  (void)in_sizes; (void)n_in; (void)ws_size;
  const float* x       = (const float*)d_in[0];
  const float* gate_w  = (const float*)d_in[1];
  const float* ebias   = (const float*)d_in[2];
  const float* w_gate  = (const float*)d_in[3];
  const float* w_up    = (const float*)d_in[4];
  const float* w_down  = (const float*)d_in[5];
  const float* sw_gate = (const float*)d_in[6];
  const float* sw_up   = (const float*)d_in[7];
  const float* sw_down = (const float*)d_in[8];
  float* out = (float*)d_out;

  char* p = (char*)d_ws;
  auto alloc = [&](size_t bytes)->char*{ char* r = p; p += (bytes + 255) & ~(size_t)255; return r; };
  u16*   xb       = (u16*)  alloc((size_t)TK*HD*2);
  u16*   P        = (u16*)  alloc((size_t)ROWS_ALL*ID*2);
  float* wdense   = (float*)alloc((size_t)TK*NE*4);
  u64*   maskbits = (u64*)  alloc((size_t)NE*32*8);
  int*   wordpfx  = (int*)  alloc((size_t)NE*32*4);
  int*   counts   = (int*)  alloc(64);
  int*   offsets  = (int*)  alloc(64);
  int*   tiles    = (int*)  alloc(MAXT*4);
  int*   rowtok   = (int*)  alloc((size_t)ROWS_ALL*4);
  float* roww     = (float*)alloc((size_t)ROWS_ALL*4);

  k_prep<<<2048, 256, 0, stream>>>(x, xb, out, out_size, maskbits);
  k_logits<<<TK, 256, 0, stream>>>(x, gate_w, ebias, wdense, maskbits);
  k_scan<<<1, 1, 0, stream>>>(maskbits, counts, offsets, wordpfx, tiles);
  k_scatter<<<dim3(TK/256, NG), 256, 0, stream>>>(maskbits, offsets, wordpfx, wdense, rowtok, roww);

  dim3 g1(ID/64, MAXT);
  dim3 g2(HD/128, MAXT);
  k_gemm1<<<g1, 256, 0, stream>>>(xb, w_gate, w_up, sw_gate, sw_up,
                                  counts, offsets, rowtok, roww, tiles, P);
  k_gemm2<<<g2, 256, 0, stream>>>(P, w_down, sw_down, counts, offsets, rowtok, tiles, out);
}

// Round 5
// 440.768 us; speedup vs baseline: 1.1110x; 1.1110x over previous
//
#include <hip/hip_runtime.h>
#include <hip/hip_bf16.h>
#include <cstdint>

#define TK 2048      // tokens (2*1024)
#define HD 2048      // hidden
#define ID 1024      // intermediate
#define NE 16        // routed experts
#define NG 17        // groups incl shared expert (g==16)
#define TOPK 4
#define SLOTS (TK*TOPK)       // 8192 routed rows
#define ROWS_ALL (SLOTS+TK)   // 10240 incl shared
#define IH (ID*HD)            // 2,097,152 elems per expert matrix
#define MAXT 96               // max M-tiles across all groups

typedef __attribute__((ext_vector_type(4))) float f32x4;
typedef __attribute__((ext_vector_type(8))) short s16x8;
typedef unsigned short u16;
typedef unsigned long long u64;

__device__ __forceinline__ u16 f2bf(float f){
  union { float f; uint32_t u; } v; v.f = f;
  uint32_t r = v.u + 0x7fffu + ((v.u >> 16) & 1u);  // RNE
  return (u16)(r >> 16);
}

// async global->LDS, 16B per lane; LDS dest is wave-uniform base + lane*16
#define GLD16(g, l) __builtin_amdgcn_global_load_lds( \
    (const __attribute__((address_space(1))) void*)(g), \
    (__attribute__((address_space(3))) void*)(l), 16, 0, 0)

// swizzled fragment pointer: 128B rows, byte ^= ((row&7)<<4)
__device__ __forceinline__ const s16x8* fragp(const u16* b, int row, int off){
  return (const s16x8*)((const char*)b + row*128 + (off ^ ((row&7)<<4)));
}

// ---------------- prep: zero out, init maskbits, convert x ----------------
__global__ void k_prep(const float* __restrict__ x, u16* __restrict__ xb,
                       float* __restrict__ out, int out_n, u64* __restrict__ maskbits){
  int gi = blockIdx.x*blockDim.x + threadIdx.x;
  int st = gridDim.x*blockDim.x;
  if (gi < NE*32) maskbits[gi] = 0ull;
  for (int i=gi; i<out_n; i+=st) out[i] = 0.f;
  for (int i=gi; i<TK*HD/4; i+=st){
    float4 f = ((const float4*)x)[i];
    ushort4 o; o.x=f2bf(f.x); o.y=f2bf(f.y); o.z=f2bf(f.z); o.w=f2bf(f.w);
    ((ushort4*)xb)[i] = o;
  }
}

// ---------------- convert all weights fp32 -> bf16 (one kernel) ----------------
__global__ void k_cvtw(const float* __restrict__ wg, const float* __restrict__ wu,
                       const float* __restrict__ wd, const float* __restrict__ swg,
                       const float* __restrict__ swu, const float* __restrict__ swd,
                       u16* __restrict__ wgb, u16* __restrict__ wub, u16* __restrict__ wdb){
  const size_t nbig = (size_t)NE*IH/4, nsml = IH/4;
  const size_t total = 3*nbig + 3*nsml;
  for (size_t i = (size_t)blockIdx.x*blockDim.x + threadIdx.x; i < total;
       i += (size_t)gridDim.x*blockDim.x){
    const float4* src; ushort4* dst; size_t j = i;
    if (j < nbig){ src=(const float4*)wg + j;  dst=(ushort4*)wgb + j; }
    else if ((j-=nbig) < nbig){ src=(const float4*)wu + j;  dst=(ushort4*)wub + j; }
    else if ((j-=nbig) < nbig){ src=(const float4*)wd + j;  dst=(ushort4*)wdb + j; }
    else if ((j-=nbig) < nsml){ src=(const float4*)swg + j; dst=(ushort4*)wgb + nbig + j; }
    else if ((j-=nsml) < nsml){ src=(const float4*)swu + j; dst=(ushort4*)wub + nbig + j; }
    else { j-=nsml; src=(const float4*)swd + j; dst=(ushort4*)wdb + nbig + j; }
    float4 f = *src;
    ushort4 o; o.x=f2bf(f.x); o.y=f2bf(f.y); o.z=f2bf(f.z); o.w=f2bf(f.w);
    *dst = o;
  }
}

// ---------------- router: logits + sigmoid + top-4 select (fused) ----------------
__global__ __launch_bounds__(256) void k_logits(const float* __restrict__ x,
                                                const float* __restrict__ gw,
                                                const float* __restrict__ bias,
                                                float* __restrict__ wdense,
                                                u64* __restrict__ maskbits){
  int t = blockIdx.x, tid = threadIdx.x;
  int lane = tid & 63, wv = tid >> 6;
  const float* xr = x + (size_t)t*HD;
  float acc[NE];
  #pragma unroll
  for (int e=0;e<NE;e++) acc[e]=0.f;
  for (int k=tid;k<HD;k+=256){
    float xv = xr[k];
    #pragma unroll
    for (int e=0;e<NE;e++) acc[e] += xv * gw[e*HD + k];
  }
  __shared__ float red[NE][4];
  #pragma unroll
  for (int e=0;e<NE;e++){
    float v = acc[e];
    #pragma unroll
    for (int off=32;off>0;off>>=1) v += __shfl_down(v, off, 64);
    if (lane==0) red[e][wv] = v;
  }
  __syncthreads();
  if (tid == 0){
    float sc[NE], bs[NE];
    #pragma unroll
    for (int e=0;e<NE;e++){
      float l = red[e][0]+red[e][1]+red[e][2]+red[e][3];
      float s = 1.f/(1.f+expf(-l));
      sc[e]=s; bs[e]=s+bias[e];
    }
    int idx[TOPK]; float wsum=0.f; unsigned used=0;
    for (int k=0;k<TOPK;k++){
      int best=0; float bv=-1e30f;
      for (int e=0;e<NE;e++) if (!((used>>e)&1u) && bs[e] > bv){ bv=bs[e]; best=e; }
      used |= 1u<<best; idx[k]=best; wsum += sc[best];
    }
    float inv = 1.f/wsum;
    for (int k=0;k<TOPK;k++){
      int e = idx[k];
      wdense[t*NE + e] = sc[e]*inv;
      atomicOr(&maskbits[e*32 + (t>>6)], 1ull << (t&63));
    }
  }
}

// prefix sums + dense tile table (tiny, 1 thread — deterministic)
__global__ void k_scan(const u64* __restrict__ maskbits, int* __restrict__ counts,
                       int* __restrict__ offsets, int* __restrict__ wordpfx,
                       int* __restrict__ tiles){
  int acc = 0;
  for (int e=0;e<NE;e++){
    int c = 0;
    for (int w=0;w<32;w++){ wordpfx[e*32+w] = c; c += __popcll(maskbits[e*32+w]); }
    counts[e] = c;
  }
  for (int e=0;e<NE;e++){ offsets[e] = acc; acc += counts[e]; }
  offsets[NE] = acc;   // == SLOTS
  counts[NE] = TK;     // shared expert
  int nt = 0;
  for (int g=0; g<NG; g++){
    int c = counts[g];
    for (int mt=0; mt*128 < c && nt < MAXT; mt++) tiles[nt++] = (g<<8) | mt;
  }
  for (; nt<MAXT; nt++) tiles[nt] = -1;
}

// deterministic compaction via popcount rank
__global__ void k_scatter(const u64* __restrict__ maskbits, const int* __restrict__ offsets,
                          const int* __restrict__ wordpfx, const float* __restrict__ wdense,
                          int* __restrict__ rowtok, float* __restrict__ roww){
  int t = blockIdx.x*blockDim.x + threadIdx.x;
  int e = blockIdx.y;
  if (t >= TK) return;
  if (e == NE){ rowtok[offsets[NE]+t] = t; roww[offsets[NE]+t] = 1.f; return; }
  u64 w = maskbits[e*32 + (t>>6)];
  if ((w >> (t&63)) & 1ull){
    int pos = offsets[e] + wordpfx[e*32 + (t>>6)] + __popcll(w & ((1ull << (t&63)) - 1ull));
    rowtok[pos] = t; roww[pos] = wdense[t*NE + e];
  }
}

// ============ GEMM1 (bf16 weights): P = silu(X Wg^T)*(X Wu^T)*roww ============
// BM=128, BN=64 (gate+up), BK=64; dbuf pipeline w/ counted vmcnt + raw barriers
__global__ __launch_bounds__(256) void k_gemm1b(
    const u16* __restrict__ xb, const u16* __restrict__ wgb, const u16* __restrict__ wub,
    const int* __restrict__ counts, const int* __restrict__ offsets,
    const int* __restrict__ rowtok, const float* __restrict__ roww,
    const int* __restrict__ tiles, u16* __restrict__ P)
{
  int te = tiles[blockIdx.y];
  if (te < 0) return;
  int g = te >> 8, mt = te & 255;
  int cnt = counts[g];
  int n0 = blockIdx.x*64;
  int base = offsets[g];
  const u16* wg16 = wgb + (size_t)g*IH;
  const u16* wu16 = wub + (size_t)g*IH;

  __shared__ u16 lsA[2][128*64];   // 2 x 16 KB
  __shared__ u16 lsG[2][64*64];    // 2 x 8 KB
  __shared__ u16 lsU[2][64*64];    // 2 x 8 KB

  int tid = threadIdx.x, lane = tid & 63, wv = tid >> 6;
  int wm = (wv>>1)*64, wn = (wv&1)*32;
  int rl = lane & 15, hi = lane >> 4;

  f32x4 accg[4][2] = {}; f32x4 accu[4][2] = {};

  // staging sources (pre-swizzled: col chunk = cb ^ (r&7)) — rule #21
  const u16* aSrc[4];
  #pragma unroll
  for (int i=0;i<4;i++){
    int b = i*256 + tid, r = b>>3, cb = b&7;
    int m = mt*128 + r; if (m >= cnt) m = cnt-1;
    int tok = rowtok[base + m];
    aSrc[i] = xb + (size_t)tok*HD + ((cb ^ (r&7))<<3);
  }
  const u16 *gSrc[2], *uSrc[2];
  #pragma unroll
  for (int i=0;i<2;i++){
    int b = i*256 + tid, r = b>>3, cb = b&7;
    size_t off = (size_t)(n0 + r)*HD + ((cb ^ (r&7))<<3);
    gSrc[i] = wg16 + off; uSrc[i] = wu16 + off;
  }

  // prologue: issue tile 0 (8 loads in flight)
  #pragma unroll
  for (int i=0;i<4;i++) GLD16(aSrc[i], &lsA[0][(i*256 + wv*64)*8]);
  #pragma unroll
  for (int i=0;i<2;i++) GLD16(gSrc[i], &lsG[0][(i*256 + wv*64)*8]);
  #pragma unroll
  for (int i=0;i<2;i++) GLD16(uSrc[i], &lsU[0][(i*256 + wv*64)*8]);

  const int ntile = HD/64;
  for (int t=0; t<ntile; ++t){
    int cur = t & 1, nxt = cur ^ 1;
    bool more = (t+1 < ntile);
    if (more){
      int k1 = (t+1)*64;
      #pragma unroll
      for (int i=0;i<4;i++) GLD16(aSrc[i]+k1, &lsA[nxt][(i*256 + wv*64)*8]);
      #pragma unroll
      for (int i=0;i<2;i++) GLD16(gSrc[i]+k1, &lsG[nxt][(i*256 + wv*64)*8]);
      #pragma unroll
      for (int i=0;i<2;i++) GLD16(uSrc[i]+k1, &lsU[nxt][(i*256 + wv*64)*8]);
      asm volatile("s_waitcnt vmcnt(8)" ::: "memory");   // tile t done; t+1 in flight
    } else {
      asm volatile("s_waitcnt vmcnt(0)" ::: "memory");
    }
    __builtin_amdgcn_s_barrier();    // tile t visible to all waves
    const u16* A = lsA[cur]; const u16* G = lsG[cur]; const u16* U = lsU[cur];
    #pragma unroll
    for (int ks=0; ks<2; ++ks){
      int off = ks*64 + hi*16;
      s16x8 af[4];
      #pragma unroll
      for (int mi=0;mi<4;mi++) af[mi] = *fragp(A, wm+16*mi+rl, off);
      #pragma unroll
      for (int ni=0;ni<2;ni++){
        s16x8 bg = *fragp(G, wn+16*ni+rl, off);
        s16x8 bu = *fragp(U, wn+16*ni+rl, off);
        #pragma unroll
        for (int mi=0;mi<4;mi++){
          accg[mi][ni] = __builtin_amdgcn_mfma_f32_16x16x32_bf16(af[mi], bg, accg[mi][ni], 0,0,0);
          accu[mi][ni] = __builtin_amdgcn_mfma_f32_16x16x32_bf16(af[mi], bu, accu[mi][ni], 0,0,0);
        }
      }
    }
    asm volatile("s_waitcnt lgkmcnt(0)" ::: "memory");   // my LDS reads done
    __builtin_amdgcn_s_barrier();    // safe to overwrite cur next iter
  }
  // epilogue: SwiGLU * token weight -> bf16 P
  int rl4 = hi*4, cl = rl;
  #pragma unroll
  for (int mi=0;mi<4;mi++){
    #pragma unroll
    for (int j=0;j<4;j++){
      int m = mt*128 + wm + mi*16 + rl4 + j;
      if (m < cnt){
        int slot = base + m;
        float wgt = roww[slot];
        #pragma unroll
        for (int ni=0;ni<2;ni++){
          float gv = accg[mi][ni][j], uv = accu[mi][ni][j];
          float pv = gv/(1.f+expf(-gv))*uv*wgt;
          P[(size_t)slot*ID + n0 + wn + ni*16 + cl] = f2bf(pv);
        }
      }
    }
  }
}

// ============ GEMM2 (bf16 weights): out[tok] += P @ Wd^T ============
// BM=128, BN=128, BK=64; same pipeline
__global__ __launch_bounds__(256) void k_gemm2b(
    const u16* __restrict__ P, const u16* __restrict__ wdb,
    const int* __restrict__ counts, const int* __restrict__ offsets,
    const int* __restrict__ rowtok, const int* __restrict__ tiles,
    float* __restrict__ out)
{
  int te = tiles[blockIdx.y];
  if (te < 0) return;
  int g = te >> 8, mt = te & 255;
  int cnt = counts[g];
  int n0 = blockIdx.x*128;
  int base = offsets[g];
  const u16* wd16 = wdb + (size_t)g*IH;

  __shared__ u16 lsA[2][128*64];   // 2 x 16 KB
  __shared__ u16 lsB[2][128*64];   // 2 x 16 KB

  int tid = threadIdx.x, lane = tid & 63, wv = tid >> 6;
  int wm = (wv>>1)*64, wn = (wv&1)*64;
  int rl = lane & 15, hi = lane >> 4;
  f32x4 acc[4][4] = {};

  const u16 *aSrc[4], *bSrc[4];
  #pragma unroll
  for (int i=0;i<4;i++){
    int b = i*256 + tid, r = b>>3, cb = b&7;
    int m = mt*128 + r; if (m >= cnt) m = cnt-1;
    aSrc[i] = P + (size_t)(base + m)*ID + ((cb ^ (r&7))<<3);
    bSrc[i] = wd16 + (size_t)(n0 + r)*ID + ((cb ^ (r&7))<<3);
  }

  #pragma unroll
  for (int i=0;i<4;i++) GLD16(aSrc[i], &lsA[0][(i*256 + wv*64)*8]);
  #pragma unroll
  for (int i=0;i<4;i++) GLD16(bSrc[i], &lsB[0][(i*256 + wv*64)*8]);

  const int ntile = ID/64;
  for (int t=0; t<ntile; ++t){
    int cur = t & 1, nxt = cur ^ 1;
    bool more = (t+1 < ntile);
    if (more){
      int k1 = (t+1)*64;
      #pragma unroll
      for (int i=0;i<4;i++) GLD16(aSrc[i]+k1, &lsA[nxt][(i*256 + wv*64)*8]);
      #pragma unroll
      for (int i=0;i<4;i++) GLD16(bSrc[i]+k1, &lsB[nxt][(i*256 + wv*64)*8]);
      asm volatile("s_waitcnt vmcnt(8)" ::: "memory");
    } else {
      asm volatile("s_waitcnt vmcnt(0)" ::: "memory");
    }
    __builtin_amdgcn_s_barrier();
    const u16* A = lsA[cur]; const u16* B = lsB[cur];
    #pragma unroll
    for (int ks=0; ks<2; ++ks){
      int off = ks*64 + hi*16;
      s16x8 af[4], bf[4];
      #pragma unroll
      for (int mi=0;mi<4;mi++) af[mi] = *fragp(A, wm+16*mi+rl, off);
      #pragma unroll
      for (int ni=0;ni<4;ni++) bf[ni] = *fragp(B, wn+16*ni+rl, off);
      #pragma unroll
      for (int mi=0;mi<4;mi++)
        #pragma unroll
        for (int ni=0;ni<4;ni++)
          acc[mi][ni] = __builtin_amdgcn_mfma_f32_16x16x32_bf16(af[mi], bf[ni], acc[mi][ni], 0,0,0);
    }
    asm volatile("s_waitcnt lgkmcnt(0)" ::: "memory");
    __builtin_amdgcn_s_barrier();
  }
  int rl4 = hi*4, cl = rl;
  #pragma unroll
  for (int mi=0;mi<4;mi++){
    #pragma unroll
    for (int j=0;j<4;j++){
      int m = mt*128 + wm + mi*16 + rl4 + j;
      if (m < cnt){
        int tok = rowtok[base + m];
        #pragma unroll
        for (int ni=0;ni<4;ni++)
          atomicAdd(&out[(size_t)tok*HD + n0 + wn + ni*16 + cl], acc[mi][ni][j]);
      }
    }
  }
}

// ---------------- host ----------------

extern "C" void kernel_launch(void* const* d_in, const int* in_sizes, int n_in,
                              void* d_out, int out_size, void* d_ws, size_t ws_size,
                              hipStream_t stream){
  (void)in_sizes; (void)n_in; (void)ws_size;
  const float* x       = (const float*)d_in[0];
  const float* gate_w  = (const float*)d_in[1];
  const float* ebias   = (const float*)d_in[2];
  const float* w_gate  = (const float*)d_in[3];
  const float* w_up    = (const float*)d_in[4];
  const float* w_down  = (const float*)d_in[5];
  const float* sw_gate = (const float*)d_in[6];
  const float* sw_up   = (const float*)d_in[7];
  const float* sw_down = (const float*)d_in[8];
  float* out = (float*)d_out;

  char* p = (char*)d_ws;
  auto alloc = [&](size_t bytes)->char*{ char* r = p; p += (bytes + 255) & ~(size_t)255; return r; };
  u16*   xb       = (u16*)  alloc((size_t)TK*HD*2);
  u16*   P        = (u16*)  alloc((size_t)ROWS_ALL*ID*2);
  float* wdense   = (float*)alloc((size_t)TK*NE*4);
  u64*   maskbits = (u64*)  alloc((size_t)NE*32*8);
  int*   wordpfx  = (int*)  alloc((size_t)NE*32*4);
  int*   counts   = (int*)  alloc(64);
  int*   offsets  = (int*)  alloc(64);
  int*   tiles    = (int*)  alloc(MAXT*4);
  int*   rowtok   = (int*)  alloc((size_t)ROWS_ALL*4);
  float* roww     = (float*)alloc((size_t)ROWS_ALL*4);
  size_t slab = (size_t)NG*IH*2;
  u16* wgb = (u16*)alloc(slab);
  u16* wub = (u16*)alloc(slab);
  u16* wdb = (u16*)alloc(slab);

  k_prep<<<2048, 256, 0, stream>>>(x, xb, out, out_size, maskbits);
  k_cvtw<<<2048, 256, 0, stream>>>(w_gate, w_up, w_down, sw_gate, sw_up, sw_down,
                                   wgb, wub, wdb);
  k_logits<<<TK, 256, 0, stream>>>(x, gate_w, ebias, wdense, maskbits);
  k_scan<<<1, 1, 0, stream>>>(maskbits, counts, offsets, wordpfx, tiles);
  k_scatter<<<dim3(TK/256, NG), 256, 0, stream>>>(maskbits, offsets, wordpfx, wdense, rowtok, roww);

  dim3 g1(ID/64, MAXT);
  dim3 g2(HD/128, MAXT);
  k_gemm1b<<<g1, 256, 0, stream>>>(xb, wgb, wub, counts, offsets, rowtok, roww, tiles, P);
  k_gemm2b<<<g2, 256, 0, stream>>>(P, wdb, counts, offsets, rowtok, tiles, out);
}